// Round 1
// baseline (9.618 us; speedup 1.0000x reference)
//
#include <hip/hip_runtime.h>
#include <math.h>

// ConvEnhanced reduces analytically to a single scalar:
//  - d is cropped to data[:2,:2] at i=0 and only zero-padded afterwards,
//    so every sum(d * dwK) is a 4-term dot with dwK's top-left 2x2.
//  - mean(softmax(x)) == 1/len(x) exactly (softmax sums to 1) -> attn_w unused.
//  - residual d.mean() over the final 7x7 = sum(crop)/49.
__global__ void ConvEnhanced_65481071405356_kernel(
    const float* __restrict__ data,
    const float* __restrict__ dw2,
    const float* __restrict__ dw3,
    const float* __restrict__ dw5,
    const float* __restrict__ dw7,
    const float* __restrict__ pw_w,
    const float* __restrict__ pw_b,
    float* __restrict__ out) {
  if (threadIdx.x != 0) return;

  // 2x2 crop of the 8x8 row-major input.
  const float c00 = data[0];
  const float c01 = data[1];
  const float c10 = data[8];
  const float c11 = data[9];
  const float sum_c = c00 + c01 + c10 + c11;

  const float* dws[4] = {dw2, dw3, dw5, dw7};
  const int ks[4] = {2, 3, 5, 7};

  float sum_sig = 0.0f;
#pragma unroll
  for (int i = 0; i < 4; ++i) {
    const float* w = dws[i];
    const int k = ks[i];
    // sum(d * dwK): d is the 2x2 crop zero-padded to k x k (k=2: full kernel).
    const float dot = c00 * w[0] + c01 * w[1] + c10 * w[k] + c11 * w[k + 1];
    const float logit = dot * pw_w[i] + pw_b[i];  // THRESHOLD == 0
    sum_sig += 1.0f / (1.0f + expf(-logit));
  }

  const float mean_out = 0.25f * sum_sig + sum_c * (1.0f / 49.0f);
  // mean(softmax) over k*k elements == 1/(k*k), exactly.
  const float attn_mean =
      0.25f * (1.0f / 4.0f + 1.0f / 9.0f + 1.0f / 25.0f + 1.0f / 49.0f);

  out[0] = mean_out * attn_mean;
}

extern "C" void kernel_launch(void* const* d_in, const int* in_sizes, int n_in,
                              void* d_out, int out_size, void* d_ws, size_t ws_size,
                              hipStream_t stream) {
  const float* data = (const float*)d_in[0];
  const float* dw2  = (const float*)d_in[1];
  const float* dw3  = (const float*)d_in[2];
  const float* dw5  = (const float*)d_in[3];
  const float* dw7  = (const float*)d_in[4];
  const float* pw_w = (const float*)d_in[5];
  const float* pw_b = (const float*)d_in[6];
  // d_in[7] = attn_w: analytically unused (mean of softmax == 1/n).
  float* out = (float*)d_out;

  ConvEnhanced_65481071405356_kernel<<<1, 64, 0, stream>>>(
      data, dw2, dw3, dw5, dw7, pw_w, pw_b, out);
}